// Round 6
// baseline (390.323 us; speedup 1.0000x reference)
//
#include <hip/hip_runtime.h>
#include <hip/hip_bf16.h>

typedef __attribute__((ext_vector_type(8))) short short8;
typedef __attribute__((ext_vector_type(4))) short short4_t;
typedef __attribute__((ext_vector_type(4))) float f32x4;

__device__ __forceinline__ short bfc(float f) {
  return __builtin_bit_cast(short, __float2bfloat16(f));
}

__device__ __forceinline__ void gll16(const void* g, void* l) {
  __builtin_amdgcn_global_load_lds((const __attribute__((address_space(1))) unsigned int*)g,
                                   (__attribute__((address_space(3))) unsigned int*)l,
                                   16, 0, 0);
}

// XOR swizzle for 64B-row (32-short) LDS tiles (GEMM staging).
__device__ __forceinline__ int swz(int row) {
  return ((((row) >> 1) ^ ((row) >> 3)) & 3) << 4;
}

// ---------------- C = A * B^T  (A: MxK, B: NxK) ----------------
// BM x 128 tile (BM = 128 or 64), BK=32, 16x16x32 bf16 MFMA.
// Wave grid 2x2; each wave owns BM/2 rows x 64 cols -> MR = BM/32 M-frags.
// A/B bf16 (gll16 staged) or fp32 (reg-staged + cvt + swizzled ds_write;
// fp32 A path only for BM=128). VSPLIT: cols >= 4096 are the V part of qkv,
// written TRANSPOSED to vtb[d][t] (d = col-4096).
template<int A_F32, int B_F32, int BF16OUT, int VSPLIT, int BM>
__global__ __launch_bounds__(256, 4)
void gemm_bt(const void* __restrict__ Av, const void* __restrict__ Bv,
             void* __restrict__ Cv, short* __restrict__ vtb,
             int M, int N, int K, int lda, int ldb, int ldc) {
  constexpr int MR = BM / 32;                 // M-frags per wave (16 rows each)
  alignas(16) __shared__ short sA[BM * 32];
  alignas(16) __shared__ short sB[128 * 32];
  const int tid = threadIdx.x;
  const int w = tid >> 6, l = tid & 63;
  const int lg = l >> 4, lr = l & 15;
  const int brow = blockIdx.y * BM, bcol = blockIdx.x * 128;
  const int wr = (w >> 1) * (BM / 2), wc = (w & 1) * 64;

  f32x4 acc[MR][4];
  #pragma unroll
  for (int m = 0; m < MR; ++m)
    #pragma unroll
    for (int n = 0; n < 4; ++n)
      acc[m][n] = (f32x4){0.f, 0.f, 0.f, 0.f};

  // bf16 staging (gll16): chunk c covers LDS bytes c*1024..+1024, lane l -> +l*16
  constexpr int ACH = (BM == 128) ? 2 : 1;
  const short* gA16[ACH]; const short* gB16[2]; short* lA16[ACH]; short* lB16[2];
  #pragma unroll
  for (int j = 0; j < ACH; ++j) {
    int c = w * ACH + j;
    int row = c * 16 + (l >> 2);
    int sb = ((l & 3) * 16) ^ swz(row);
    if (!A_F32) { gA16[j] = (const short*)Av + (size_t)(brow + row) * lda + sb / 2; lA16[j] = sA + c * 512; }
  }
  #pragma unroll
  for (int j = 0; j < 2; ++j) {
    int c = w * 2 + j;
    int row = c * 16 + (l >> 2);
    int sb = ((l & 3) * 16) ^ swz(row);
    if (!B_F32) { gB16[j] = (const short*)Bv + (size_t)(bcol + row) * ldb + sb / 2; lB16[j] = sB + c * 512; }
  }

  // fp32 staging (BM=128 layout): thread t -> row t>>1, col half (t&1)*16
  const int srow = tid >> 1, scg = tid & 1;
  const float* gA32 = (A_F32 && BM == 128) ? (const float*)Av + (size_t)(brow + srow) * lda + scg * 16 : nullptr;
  const float* gB32 = B_F32 ? (const float*)Bv + (size_t)(bcol + srow) * ldb + scg * 16 : nullptr;
  float4 pa[4], pb[4];
  if (A_F32) {
    #pragma unroll
    for (int q = 0; q < 4; ++q) pa[q] = *(const float4*)(gA32 + q * 4);
  }
  if (B_F32) {
    #pragma unroll
    for (int q = 0; q < 4; ++q) pb[q] = *(const float4*)(gB32 + q * 4);
  }

  int aoff[MR], boff[4];
  #pragma unroll
  for (int m = 0; m < MR; ++m) {
    int ra = wr + m * 16 + lr;
    aoff[m] = ra * 64 + ((lg * 16) ^ swz(ra));
  }
  #pragma unroll
  for (int n = 0; n < 4; ++n) {
    int rb = wc + n * 16 + lr;
    boff[n] = rb * 64 + ((lg * 16) ^ swz(rb));
  }

  for (int k0 = 0; k0 < K; k0 += 32) {
    if (A_F32) {
      short8 s0, s1;
      s0[0]=bfc(pa[0].x); s0[1]=bfc(pa[0].y); s0[2]=bfc(pa[0].z); s0[3]=bfc(pa[0].w);
      s0[4]=bfc(pa[1].x); s0[5]=bfc(pa[1].y); s0[6]=bfc(pa[1].z); s0[7]=bfc(pa[1].w);
      s1[0]=bfc(pa[2].x); s1[1]=bfc(pa[2].y); s1[2]=bfc(pa[2].z); s1[3]=bfc(pa[2].w);
      s1[4]=bfc(pa[3].x); s1[5]=bfc(pa[3].y); s1[6]=bfc(pa[3].z); s1[7]=bfc(pa[3].w);
      char* base = (char*)sA + srow * 64;
      *(short8*)(base + ((scg * 32 +  0) ^ swz(srow))) = s0;
      *(short8*)(base + ((scg * 32 + 16) ^ swz(srow))) = s1;
    } else {
      #pragma unroll
      for (int j = 0; j < ACH; ++j) gll16(gA16[j] + k0, lA16[j]);
    }
    if (B_F32) {
      short8 s0, s1;
      s0[0]=bfc(pb[0].x); s0[1]=bfc(pb[0].y); s0[2]=bfc(pb[0].z); s0[3]=bfc(pb[0].w);
      s0[4]=bfc(pb[1].x); s0[5]=bfc(pb[1].y); s0[6]=bfc(pb[1].z); s0[7]=bfc(pb[1].w);
      s1[0]=bfc(pb[2].x); s1[1]=bfc(pb[2].y); s1[2]=bfc(pb[2].z); s1[3]=bfc(pb[2].w);
      s1[4]=bfc(pb[3].x); s1[5]=bfc(pb[3].y); s1[6]=bfc(pb[3].z); s1[7]=bfc(pb[3].w);
      char* base = (char*)sB + srow * 64;
      *(short8*)(base + ((scg * 32 +  0) ^ swz(srow))) = s0;
      *(short8*)(base + ((scg * 32 + 16) ^ swz(srow))) = s1;
    } else {
      gll16(gB16[0] + k0, lB16[0]); gll16(gB16[1] + k0, lB16[1]);
    }
    __syncthreads();

    short8 af[MR], bfr[4];
    #pragma unroll
    for (int m = 0; m < MR; ++m) af[m] = *(const short8*)((const char*)sA + aoff[m]);
    #pragma unroll
    for (int n = 0; n < 4; ++n) bfr[n] = *(const short8*)((const char*)sB + boff[n]);

    if (k0 + 32 < K) {
      if (A_F32) {
        #pragma unroll
        for (int q = 0; q < 4; ++q) pa[q] = *(const float4*)(gA32 + k0 + 32 + q * 4);
      }
      if (B_F32) {
        #pragma unroll
        for (int q = 0; q < 4; ++q) pb[q] = *(const float4*)(gB32 + k0 + 32 + q * 4);
      }
    }

    #pragma unroll
    for (int m = 0; m < MR; ++m)
      #pragma unroll
      for (int n = 0; n < 4; ++n)
        acc[m][n] = __builtin_amdgcn_mfma_f32_16x16x32_bf16(af[m], bfr[n], acc[m][n], 0, 0, 0);
    __syncthreads();
  }

  // epilogue
  const bool vpart = VSPLIT && (bcol >= 4096);
  #pragma unroll
  for (int m = 0; m < MR; ++m)
    #pragma unroll
    for (int n = 0; n < 4; ++n) {
      if (vpart) {
        int d = bcol + wc + n * 16 + lr - 4096;
        int t0 = brow + wr + m * 16 + lg * 4;
        short4_t pk;
        pk[0] = bfc(acc[m][n][0]); pk[1] = bfc(acc[m][n][1]);
        pk[2] = bfc(acc[m][n][2]); pk[3] = bfc(acc[m][n][3]);
        *(short4_t*)(vtb + (size_t)d * 2048 + t0) = pk;
      } else {
        #pragma unroll
        for (int j = 0; j < 4; ++j) {
          size_t idx = (size_t)(brow + wr + m * 16 + lg * 4 + j) * ldc + (bcol + wc + n * 16 + lr);
          if (BF16OUT) ((short*)Cv)[idx] = bfc(acc[m][n][j]);
          else         ((float*)Cv)[idx] = acc[m][n][j];
        }
      }
    }
}

// ---------------- causal flash attention ----------------
// qkv: [2048][6144] bf16 (Q|K|_ per head). vt: [2048 d][2048 t] bf16 (V^T).
// y written into qkv's V region (cols 4096+, stride 6144).
__global__ __launch_bounds__(256, 2)
void attn_fwd(const short* __restrict__ qkv, const short* __restrict__ vt,
              short* __restrict__ ybase) {
  constexpr int LDQ = 6144;
  const int h = blockIdx.y;
  const int qb = (h < 8) ? (int)blockIdx.x : 31 - (int)blockIdx.x;
  const int tid = threadIdx.x;
  const int w = tid >> 6, l = tid & 63;
  const int lg = l >> 4, lr = l & 15;
  const f32x4 fzero = {0.f, 0.f, 0.f, 0.f};

  alignas(16) __shared__ short sK[2][64 * 128];    // [kv][feature], XOR ((row&7)<<4)
  alignas(16) __shared__ short sVt[2][128 * 64];   // [d][kv], XOR ((d&7)<<4)
  alignas(16) __shared__ short sP[4][16][72];      // per-wave P, row stride 144B

  const int qrow0 = qb * 64 + w * 16;
  short8 qf[4];
  #pragma unroll
  for (int kk = 0; kk < 4; ++kk)
    qf[kk] = *(const short8*)(qkv + (size_t)(qrow0 + lr) * LDQ + h * 128 + kk * 32 + lg * 8);

  float m_run[4] = {-1e30f, -1e30f, -1e30f, -1e30f};
  float l_run[4] = {0.f, 0.f, 0.f, 0.f};
  f32x4 yacc[8];
  #pragma unroll
  for (int dt = 0; dt < 8; ++dt) yacc[dt] = fzero;

  const short* gK[4]; const short* gV[4]; int loff[4];
  #pragma unroll
  for (int j = 0; j < 4; ++j) {
    int c = w * 4 + j;
    loff[j] = c * 1024 + l * 16;
    int rk = c * 4 + (l >> 4);
    int sbk = ((l & 15) * 16) ^ ((rk & 7) << 4);
    gK[j] = qkv + (size_t)rk * LDQ + 2048 + h * 128 + sbk / 2;
    int rv = c * 8 + (l >> 3);
    int sbv = ((l & 7) * 16) ^ (((l >> 3) & 7) << 4);
    gV[j] = vt + (size_t)(h * 128 + rv) * 2048 + sbv / 2;
  }

  const float scale = 0.088388347648318447f;   // 1/sqrt(128)

  #pragma unroll
  for (int j = 0; j < 4; ++j) {
    gll16(gK[j], (char*)sK[0] + loff[j]);
    gll16(gV[j], (char*)sVt[0] + loff[j]);
  }

  for (int kb = 0; kb <= qb; ++kb) {
    const int cur = kb & 1;
    __syncthreads();

    if (kb < qb) {
      const size_t koff = (size_t)(kb + 1) * 64 * LDQ;
      const int voff = (kb + 1) * 64;
      #pragma unroll
      for (int j = 0; j < 4; ++j) {
        gll16(gK[j] + koff, (char*)sK[cur ^ 1] + loff[j]);
        gll16(gV[j] + voff, (char*)sVt[cur ^ 1] + loff[j]);
      }
    }

    f32x4 st[4];
    __builtin_amdgcn_s_setprio(1);
    #pragma unroll
    for (int ct = 0; ct < 4; ++ct) {
      f32x4 a = fzero;
      int row = ct * 16 + lr;
      #pragma unroll
      for (int kk = 0; kk < 4; ++kk) {
        int cb = (kk * 64 + lg * 16) ^ ((row & 7) << 4);
        short8 kf = *(const short8*)((const char*)sK[cur] + row * 256 + cb);
        a = __builtin_amdgcn_mfma_f32_16x16x32_bf16(qf[kk], kf, a, 0, 0, 0);
      }
      st[ct] = a;
    }
    __builtin_amdgcn_s_setprio(0);

    const bool diag = (kb == qb);
    float p[4][4];
    #pragma unroll
    for (int j = 0; j < 4; ++j) {
      const int grow = qrow0 + lg * 4 + j;
      float mx = -1e30f;
      #pragma unroll
      for (int ct = 0; ct < 4; ++ct) {
        float sv = st[ct][j] * scale;
        if (diag && (kb * 64 + ct * 16 + lr > grow)) sv = -1e30f;
        p[j][ct] = sv;
        mx = fmaxf(mx, sv);
      }
      #pragma unroll
      for (int off = 1; off < 16; off <<= 1) mx = fmaxf(mx, __shfl_xor(mx, off));
      if (__any(mx > m_run[j] + 8.f)) {
        float mnew = fmaxf(m_run[j], mx);
        float sc = __expf(m_run[j] - mnew);
        m_run[j] = mnew;
        l_run[j] *= sc;
        #pragma unroll
        for (int dt = 0; dt < 8; ++dt) yacc[dt][j] *= sc;
      }
      float sum = 0.f;
      #pragma unroll
      for (int ct = 0; ct < 4; ++ct) { float e = __expf(p[j][ct] - m_run[j]); p[j][ct] = e; sum += e; }
      #pragma unroll
      for (int off = 1; off < 16; off <<= 1) sum += __shfl_xor(sum, off);
      l_run[j] += sum;
    }

    #pragma unroll
    for (int j = 0; j < 4; ++j)
      #pragma unroll
      for (int ct = 0; ct < 4; ++ct)
        sP[w][lg * 4 + j][ct * 16 + lr] = bfc(p[j][ct]);
    asm volatile("s_waitcnt lgkmcnt(0)" ::: "memory");
    __builtin_amdgcn_sched_barrier(0);

    __builtin_amdgcn_s_setprio(1);
    #pragma unroll
    for (int dt = 0; dt < 8; ++dt) {
      int d = dt * 16 + lr;
      #pragma unroll
      for (int ks = 0; ks < 2; ++ks) {
        short8 pa = *(const short8*)(&sP[w][lr][ks * 32 + lg * 8]);
        int cb = (ks * 64 + lg * 16) ^ ((d & 7) << 4);
        short8 vf = *(const short8*)((const char*)sVt[cur] + d * 128 + cb);
        yacc[dt] = __builtin_amdgcn_mfma_f32_16x16x32_bf16(pa, vf, yacc[dt], 0, 0, 0);
      }
    }
    __builtin_amdgcn_s_setprio(0);
  }

  #pragma unroll
  for (int j = 0; j < 4; ++j) {
    float inv = 1.f / l_run[j];
    int grow = qrow0 + lg * 4 + j;
    #pragma unroll
    for (int dt = 0; dt < 8; ++dt)
      ybase[(size_t)grow * LDQ + 4096 + h * 128 + dt * 16 + lr] = bfc(yacc[dt][j] * inv);
  }
}

// ---------------- launch ----------------
extern "C" void kernel_launch(void* const* d_in, const int* in_sizes, int n_in,
                              void* d_out, int out_size, void* d_ws, size_t ws_size,
                              hipStream_t stream) {
  const float* x      = (const float*)d_in[0];
  const float* w_attn = (const float*)d_in[1];
  const float* w_proj = (const float*)d_in[2];
  float* out = (float*)d_out;
  char* ws = (char*)d_ws;

  // ws: qkvb 24 MiB (Q|K cols 0..4095; V region holds y after attention)
  //     vtb  8 MiB  (V^T, [2048 d][2048 t])        total exactly 32 MiB
  short* qkvb = (short*)(ws);
  short* vtb  = (short*)(ws + 25165824);

  // qkv = x @ w_attn^T; V part written transposed into vtb. 768 blocks -> 3/CU.
  gemm_bt<1, 1, 1, 1, 128><<<dim3(48, 16), dim3(256), 0, stream>>>(
      x, w_attn, (void*)qkvb, vtb, 2048, 6144, 2048, 2048, 2048, 6144);

  // flash attention; y -> qkvb's V region (stride 6144)
  attn_fwd<<<dim3(32, 16), dim3(256), 0, stream>>>(qkvb, vtb, qkvb);

  // out = y @ w_proj^T, 64x128 tile -> 512 blocks -> 2/CU.
  gemm_bt<0, 1, 0, 0, 64><<<dim3(16, 32), dim3(256), 0, stream>>>(
      (const void*)(qkvb + 4096), w_proj, (void*)out, nullptr, 2048, 2048, 2048, 6144, 2048, 2048);
}

// Round 7
// 278.397 us; speedup vs baseline: 1.4020x; 1.4020x over previous
//
#include <hip/hip_runtime.h>
#include <hip/hip_bf16.h>

typedef __attribute__((ext_vector_type(8))) short short8;
typedef __attribute__((ext_vector_type(4))) short short4_t;
typedef __attribute__((ext_vector_type(4))) float f32x4;

__device__ __forceinline__ short bfc(float f) {
  return __builtin_bit_cast(short, __float2bfloat16(f));
}

__device__ __forceinline__ void gll16(const void* g, void* l) {
  __builtin_amdgcn_global_load_lds((const __attribute__((address_space(1))) unsigned int*)g,
                                   (__attribute__((address_space(3))) unsigned int*)l,
                                   16, 0, 0);
}

// XOR swizzle for 64B-row (32-short) LDS tiles (BK=32 staging).
__device__ __forceinline__ int swz(int row) {
  return ((((row) >> 1) ^ ((row) >> 3)) & 3) << 4;
}

// ---------------- fp32 -> bf16 convert (grid-stride, float4x2 -> short8) ----
__global__ void cvt_bf16(const float* __restrict__ in, short* __restrict__ out, int n8) {
  int i = blockIdx.x * blockDim.x + threadIdx.x;
  int stride = gridDim.x * blockDim.x;
  for (; i < n8; i += stride) {
    float4 a = ((const float4*)in)[2 * i];
    float4 b = ((const float4*)in)[2 * i + 1];
    short8 o;
    o[0] = bfc(a.x); o[1] = bfc(a.y); o[2] = bfc(a.z); o[3] = bfc(a.w);
    o[4] = bfc(b.x); o[5] = bfc(b.y); o[6] = bfc(b.z); o[7] = bfc(b.w);
    ((short8*)out)[i] = o;
  }
}

// ---------------- all-bf16 GEMM: C = A * B^T, BM x 128 tile, BK=64 ----------
// Both operands staged via gll16 (128B rows, XOR ((row&7)<<4) on source & read).
// 32 K-steps (half the barrier drains of BK=32). VSPLIT: cols >= 4096 go
// transposed to vtb[d][t].
template<int BF16OUT, int VSPLIT, int BM>
__global__ __launch_bounds__(256, 2)
void gemm_bb(const short* __restrict__ A, const short* __restrict__ B,
             void* __restrict__ Cv, short* __restrict__ vtb,
             int M, int N, int K, int lda, int ldb, int ldc) {
  constexpr int MR = BM / 32;                 // M-frags per wave
  constexpr int ACH = BM / 32;                // A staging chunks per wave (1KB each)
  alignas(16) __shared__ short sA[BM * 64];
  alignas(16) __shared__ short sB[128 * 64];
  const int tid = threadIdx.x;
  const int w = tid >> 6, l = tid & 63;
  const int lg = l >> 4, lr = l & 15;
  const int brow = blockIdx.y * BM, bcol = blockIdx.x * 128;
  const int wr = (w >> 1) * (BM / 2), wc = (w & 1) * 64;

  f32x4 acc[MR][4];
  #pragma unroll
  for (int m = 0; m < MR; ++m)
    #pragma unroll
    for (int n = 0; n < 4; ++n)
      acc[m][n] = (f32x4){0.f, 0.f, 0.f, 0.f};

  // staging: chunk c = 8 rows x 128B; lane l -> row c*8+(l>>3), 16B at ((l&7)*16)^((row&7)<<4)
  const short* gA[ACH]; short* lA[ACH];
  #pragma unroll
  for (int j = 0; j < ACH; ++j) {
    int c = w * ACH + j;
    int row = c * 8 + (l >> 3);
    int sb = ((l & 7) * 16) ^ ((row & 7) << 4);
    gA[j] = A + (size_t)(brow + row) * lda + sb / 2;
    lA[j] = sA + c * 512;
  }
  const short* gB[4]; short* lB[4];
  #pragma unroll
  for (int j = 0; j < 4; ++j) {
    int c = w * 4 + j;
    int row = c * 8 + (l >> 3);
    int sb = ((l & 7) * 16) ^ ((row & 7) << 4);
    gB[j] = B + (size_t)(bcol + row) * ldb + sb / 2;
    lB[j] = sB + c * 512;
  }

  for (int k0 = 0; k0 < K; k0 += 64) {
    #pragma unroll
    for (int j = 0; j < ACH; ++j) gll16(gA[j] + k0, lA[j]);
    #pragma unroll
    for (int j = 0; j < 4; ++j) gll16(gB[j] + k0, lB[j]);
    __syncthreads();

    #pragma unroll
    for (int kk = 0; kk < 2; ++kk) {
      short8 af[MR], bfr[4];
      #pragma unroll
      for (int m = 0; m < MR; ++m) {
        int ra = wr + m * 16 + lr;
        af[m] = *(const short8*)((const char*)sA + ra * 128 + ((kk * 64 + lg * 16) ^ ((ra & 7) << 4)));
      }
      #pragma unroll
      for (int n = 0; n < 4; ++n) {
        int rb = wc + n * 16 + lr;
        bfr[n] = *(const short8*)((const char*)sB + rb * 128 + ((kk * 64 + lg * 16) ^ ((rb & 7) << 4)));
      }
      #pragma unroll
      for (int m = 0; m < MR; ++m)
        #pragma unroll
        for (int n = 0; n < 4; ++n)
          acc[m][n] = __builtin_amdgcn_mfma_f32_16x16x32_bf16(af[m], bfr[n], acc[m][n], 0, 0, 0);
    }
    __syncthreads();
  }

  const bool vpart = VSPLIT && (bcol >= 4096);
  #pragma unroll
  for (int m = 0; m < MR; ++m)
    #pragma unroll
    for (int n = 0; n < 4; ++n) {
      if (vpart) {
        int d = bcol + wc + n * 16 + lr - 4096;
        int t0 = brow + wr + m * 16 + lg * 4;
        short4_t pk;
        pk[0] = bfc(acc[m][n][0]); pk[1] = bfc(acc[m][n][1]);
        pk[2] = bfc(acc[m][n][2]); pk[3] = bfc(acc[m][n][3]);
        *(short4_t*)(vtb + (size_t)d * 2048 + t0) = pk;
      } else {
        #pragma unroll
        for (int j = 0; j < 4; ++j) {
          size_t idx = (size_t)(brow + wr + m * 16 + lg * 4 + j) * ldc + (bcol + wc + n * 16 + lr);
          if (BF16OUT) ((short*)Cv)[idx] = bfc(acc[m][n][j]);
          else         ((float*)Cv)[idx] = acc[m][n][j];
        }
      }
    }
}

// ---------------- fallback GEMM (fp32 operands fused-convert, BK=32) --------
template<int A_F32, int B_F32, int BF16OUT, int VSPLIT, int BM>
__global__ __launch_bounds__(256, 2)
void gemm_bt(const void* __restrict__ Av, const void* __restrict__ Bv,
             void* __restrict__ Cv, short* __restrict__ vtb,
             int M, int N, int K, int lda, int ldb, int ldc) {
  constexpr int MR = BM / 32;
  alignas(16) __shared__ short sA[BM * 32];
  alignas(16) __shared__ short sB[128 * 32];
  const int tid = threadIdx.x;
  const int w = tid >> 6, l = tid & 63;
  const int lg = l >> 4, lr = l & 15;
  const int brow = blockIdx.y * BM, bcol = blockIdx.x * 128;
  const int wr = (w >> 1) * (BM / 2), wc = (w & 1) * 64;

  f32x4 acc[MR][4];
  #pragma unroll
  for (int m = 0; m < MR; ++m)
    #pragma unroll
    for (int n = 0; n < 4; ++n)
      acc[m][n] = (f32x4){0.f, 0.f, 0.f, 0.f};

  constexpr int ACH = (BM == 128) ? 2 : 1;
  const short* gA16[ACH]; const short* gB16[2]; short* lA16[ACH]; short* lB16[2];
  #pragma unroll
  for (int j = 0; j < ACH; ++j) {
    int c = w * ACH + j;
    int row = c * 16 + (l >> 2);
    int sb = ((l & 3) * 16) ^ swz(row);
    if (!A_F32) { gA16[j] = (const short*)Av + (size_t)(brow + row) * lda + sb / 2; lA16[j] = sA + c * 512; }
  }
  #pragma unroll
  for (int j = 0; j < 2; ++j) {
    int c = w * 2 + j;
    int row = c * 16 + (l >> 2);
    int sb = ((l & 3) * 16) ^ swz(row);
    if (!B_F32) { gB16[j] = (const short*)Bv + (size_t)(bcol + row) * ldb + sb / 2; lB16[j] = sB + c * 512; }
  }

  const int srow = tid >> 1, scg = tid & 1;
  const float* gA32 = (A_F32 && BM == 128) ? (const float*)Av + (size_t)(brow + srow) * lda + scg * 16 : nullptr;
  const float* gB32 = B_F32 ? (const float*)Bv + (size_t)(bcol + srow) * ldb + scg * 16 : nullptr;
  float4 pa[4], pb[4];
  if (A_F32) {
    #pragma unroll
    for (int q = 0; q < 4; ++q) pa[q] = *(const float4*)(gA32 + q * 4);
  }
  if (B_F32) {
    #pragma unroll
    for (int q = 0; q < 4; ++q) pb[q] = *(const float4*)(gB32 + q * 4);
  }

  int aoff[MR], boff[4];
  #pragma unroll
  for (int m = 0; m < MR; ++m) {
    int ra = wr + m * 16 + lr;
    aoff[m] = ra * 64 + ((lg * 16) ^ swz(ra));
  }
  #pragma unroll
  for (int n = 0; n < 4; ++n) {
    int rb = wc + n * 16 + lr;
    boff[n] = rb * 64 + ((lg * 16) ^ swz(rb));
  }

  for (int k0 = 0; k0 < K; k0 += 32) {
    if (A_F32) {
      short8 s0, s1;
      s0[0]=bfc(pa[0].x); s0[1]=bfc(pa[0].y); s0[2]=bfc(pa[0].z); s0[3]=bfc(pa[0].w);
      s0[4]=bfc(pa[1].x); s0[5]=bfc(pa[1].y); s0[6]=bfc(pa[1].z); s0[7]=bfc(pa[1].w);
      s1[0]=bfc(pa[2].x); s1[1]=bfc(pa[2].y); s1[2]=bfc(pa[2].z); s1[3]=bfc(pa[2].w);
      s1[4]=bfc(pa[3].x); s1[5]=bfc(pa[3].y); s1[6]=bfc(pa[3].z); s1[7]=bfc(pa[3].w);
      char* base = (char*)sA + srow * 64;
      *(short8*)(base + ((scg * 32 +  0) ^ swz(srow))) = s0;
      *(short8*)(base + ((scg * 32 + 16) ^ swz(srow))) = s1;
    } else {
      #pragma unroll
      for (int j = 0; j < ACH; ++j) gll16(gA16[j] + k0, lA16[j]);
    }
    if (B_F32) {
      short8 s0, s1;
      s0[0]=bfc(pb[0].x); s0[1]=bfc(pb[0].y); s0[2]=bfc(pb[0].z); s0[3]=bfc(pb[0].w);
      s0[4]=bfc(pb[1].x); s0[5]=bfc(pb[1].y); s0[6]=bfc(pb[1].z); s0[7]=bfc(pb[1].w);
      s1[0]=bfc(pb[2].x); s1[1]=bfc(pb[2].y); s1[2]=bfc(pb[2].z); s1[3]=bfc(pb[2].w);
      s1[4]=bfc(pb[3].x); s1[5]=bfc(pb[3].y); s1[6]=bfc(pb[3].z); s1[7]=bfc(pb[3].w);
      char* base = (char*)sB + srow * 64;
      *(short8*)(base + ((scg * 32 +  0) ^ swz(srow))) = s0;
      *(short8*)(base + ((scg * 32 + 16) ^ swz(srow))) = s1;
    } else {
      gll16(gB16[0] + k0, lB16[0]); gll16(gB16[1] + k0, lB16[1]);
    }
    __syncthreads();

    short8 af[MR], bfr[4];
    #pragma unroll
    for (int m = 0; m < MR; ++m) af[m] = *(const short8*)((const char*)sA + aoff[m]);
    #pragma unroll
    for (int n = 0; n < 4; ++n) bfr[n] = *(const short8*)((const char*)sB + boff[n]);

    if (k0 + 32 < K) {
      if (A_F32) {
        #pragma unroll
        for (int q = 0; q < 4; ++q) pa[q] = *(const float4*)(gA32 + k0 + 32 + q * 4);
      }
      if (B_F32) {
        #pragma unroll
        for (int q = 0; q < 4; ++q) pb[q] = *(const float4*)(gB32 + k0 + 32 + q * 4);
      }
    }

    #pragma unroll
    for (int m = 0; m < MR; ++m)
      #pragma unroll
      for (int n = 0; n < 4; ++n)
        acc[m][n] = __builtin_amdgcn_mfma_f32_16x16x32_bf16(af[m], bfr[n], acc[m][n], 0, 0, 0);
    __syncthreads();
  }

  const bool vpart = VSPLIT && (bcol >= 4096);
  #pragma unroll
  for (int m = 0; m < MR; ++m)
    #pragma unroll
    for (int n = 0; n < 4; ++n) {
      if (vpart) {
        int d = bcol + wc + n * 16 + lr - 4096;
        int t0 = brow + wr + m * 16 + lg * 4;
        short4_t pk;
        pk[0] = bfc(acc[m][n][0]); pk[1] = bfc(acc[m][n][1]);
        pk[2] = bfc(acc[m][n][2]); pk[3] = bfc(acc[m][n][3]);
        *(short4_t*)(vtb + (size_t)d * 2048 + t0) = pk;
      } else {
        #pragma unroll
        for (int j = 0; j < 4; ++j) {
          size_t idx = (size_t)(brow + wr + m * 16 + lg * 4 + j) * ldc + (bcol + wc + n * 16 + lr);
          if (BF16OUT) ((short*)Cv)[idx] = bfc(acc[m][n][j]);
          else         ((float*)Cv)[idx] = acc[m][n][j];
        }
      }
    }
}

// ---------------- causal flash attention ----------------
__global__ __launch_bounds__(256, 2)
void attn_fwd(const short* __restrict__ qkv, const short* __restrict__ vt,
              short* __restrict__ ybase) {
  constexpr int LDQ = 6144;
  const int h = blockIdx.y;
  const int qb = (h < 8) ? (int)blockIdx.x : 31 - (int)blockIdx.x;
  const int tid = threadIdx.x;
  const int w = tid >> 6, l = tid & 63;
  const int lg = l >> 4, lr = l & 15;
  const f32x4 fzero = {0.f, 0.f, 0.f, 0.f};

  alignas(16) __shared__ short sK[2][64 * 128];
  alignas(16) __shared__ short sVt[2][128 * 64];
  alignas(16) __shared__ short sP[4][16][72];

  const int qrow0 = qb * 64 + w * 16;
  short8 qf[4];
  #pragma unroll
  for (int kk = 0; kk < 4; ++kk)
    qf[kk] = *(const short8*)(qkv + (size_t)(qrow0 + lr) * LDQ + h * 128 + kk * 32 + lg * 8);

  float m_run[4] = {-1e30f, -1e30f, -1e30f, -1e30f};
  float l_run[4] = {0.f, 0.f, 0.f, 0.f};
  f32x4 yacc[8];
  #pragma unroll
  for (int dt = 0; dt < 8; ++dt) yacc[dt] = fzero;

  const short* gK[4]; const short* gV[4]; int loff[4];
  #pragma unroll
  for (int j = 0; j < 4; ++j) {
    int c = w * 4 + j;
    loff[j] = c * 1024 + l * 16;
    int rk = c * 4 + (l >> 4);
    int sbk = ((l & 15) * 16) ^ ((rk & 7) << 4);
    gK[j] = qkv + (size_t)rk * LDQ + 2048 + h * 128 + sbk / 2;
    int rv = c * 8 + (l >> 3);
    int sbv = ((l & 7) * 16) ^ (((l >> 3) & 7) << 4);
    gV[j] = vt + (size_t)(h * 128 + rv) * 2048 + sbv / 2;
  }

  const float scale = 0.088388347648318447f;

  #pragma unroll
  for (int j = 0; j < 4; ++j) {
    gll16(gK[j], (char*)sK[0] + loff[j]);
    gll16(gV[j], (char*)sVt[0] + loff[j]);
  }

  for (int kb = 0; kb <= qb; ++kb) {
    const int cur = kb & 1;
    __syncthreads();

    if (kb < qb) {
      const size_t koff = (size_t)(kb + 1) * 64 * LDQ;
      const int voff = (kb + 1) * 64;
      #pragma unroll
      for (int j = 0; j < 4; ++j) {
        gll16(gK[j] + koff, (char*)sK[cur ^ 1] + loff[j]);
        gll16(gV[j] + voff, (char*)sVt[cur ^ 1] + loff[j]);
      }
    }

    f32x4 st[4];
    __builtin_amdgcn_s_setprio(1);
    #pragma unroll
    for (int ct = 0; ct < 4; ++ct) {
      f32x4 a = fzero;
      int row = ct * 16 + lr;
      #pragma unroll
      for (int kk = 0; kk < 4; ++kk) {
        int cb = (kk * 64 + lg * 16) ^ ((row & 7) << 4);
        short8 kf = *(const short8*)((const char*)sK[cur] + row * 256 + cb);
        a = __builtin_amdgcn_mfma_f32_16x16x32_bf16(qf[kk], kf, a, 0, 0, 0);
      }
      st[ct] = a;
    }
    __builtin_amdgcn_s_setprio(0);

    const bool diag = (kb == qb);
    float p[4][4];
    #pragma unroll
    for (int j = 0; j < 4; ++j) {
      const int grow = qrow0 + lg * 4 + j;
      float mx = -1e30f;
      #pragma unroll
      for (int ct = 0; ct < 4; ++ct) {
        float sv = st[ct][j] * scale;
        if (diag && (kb * 64 + ct * 16 + lr > grow)) sv = -1e30f;
        p[j][ct] = sv;
        mx = fmaxf(mx, sv);
      }
      #pragma unroll
      for (int off = 1; off < 16; off <<= 1) mx = fmaxf(mx, __shfl_xor(mx, off));
      if (__any(mx > m_run[j] + 8.f)) {
        float mnew = fmaxf(m_run[j], mx);
        float sc = __expf(m_run[j] - mnew);
        m_run[j] = mnew;
        l_run[j] *= sc;
        #pragma unroll
        for (int dt = 0; dt < 8; ++dt) yacc[dt][j] *= sc;
      }
      float sum = 0.f;
      #pragma unroll
      for (int ct = 0; ct < 4; ++ct) { float e = __expf(p[j][ct] - m_run[j]); p[j][ct] = e; sum += e; }
      #pragma unroll
      for (int off = 1; off < 16; off <<= 1) sum += __shfl_xor(sum, off);
      l_run[j] += sum;
    }

    #pragma unroll
    for (int j = 0; j < 4; ++j)
      #pragma unroll
      for (int ct = 0; ct < 4; ++ct)
        sP[w][lg * 4 + j][ct * 16 + lr] = bfc(p[j][ct]);
    asm volatile("s_waitcnt lgkmcnt(0)" ::: "memory");
    __builtin_amdgcn_sched_barrier(0);

    __builtin_amdgcn_s_setprio(1);
    #pragma unroll
    for (int dt = 0; dt < 8; ++dt) {
      int d = dt * 16 + lr;
      #pragma unroll
      for (int ks = 0; ks < 2; ++ks) {
        short8 pa = *(const short8*)(&sP[w][lr][ks * 32 + lg * 8]);
        int cb = (ks * 64 + lg * 16) ^ ((d & 7) << 4);
        short8 vf = *(const short8*)((const char*)sVt[cur] + d * 128 + cb);
        yacc[dt] = __builtin_amdgcn_mfma_f32_16x16x32_bf16(pa, vf, yacc[dt], 0, 0, 0);
      }
    }
    __builtin_amdgcn_s_setprio(0);
  }

  #pragma unroll
  for (int j = 0; j < 4; ++j) {
    float inv = 1.f / l_run[j];
    int grow = qrow0 + lg * 4 + j;
    #pragma unroll
    for (int dt = 0; dt < 8; ++dt)
      ybase[(size_t)grow * LDQ + 4096 + h * 128 + dt * 16 + lr] = bfc(yacc[dt][j] * inv);
  }
}

// ---------------- launch ----------------
extern "C" void kernel_launch(void* const* d_in, const int* in_sizes, int n_in,
                              void* d_out, int out_size, void* d_ws, size_t ws_size,
                              hipStream_t stream) {
  const float* x      = (const float*)d_in[0];
  const float* w_attn = (const float*)d_in[1];
  const float* w_proj = (const float*)d_in[2];
  float* out = (float*)d_out;
  char* ws = (char*)d_ws;

  // base layout (32 MiB): qkvb 24 MiB | vtb 8 MiB
  short* qkvb = (short*)(ws);
  short* vtb  = (short*)(ws + 25165824);

  if (ws_size >= (size_t)75497472) {
    // fast path (72 MiB): + xb 8 | wab 24 | wpb 8
    short* xb  = (short*)(ws + 33554432);
    short* wab = (short*)(ws + 41943040);
    short* wpb = (short*)(ws + 67108864);
    cvt_bf16<<<dim3(2048), dim3(256), 0, stream>>>(x,      xb,   524288);
    cvt_bf16<<<dim3(2048), dim3(256), 0, stream>>>(w_attn, wab, 1572864);
    cvt_bf16<<<dim3(2048), dim3(256), 0, stream>>>(w_proj, wpb,  524288);

    gemm_bb<1, 1, 128><<<dim3(48, 16), dim3(256), 0, stream>>>(
        xb, wab, (void*)qkvb, vtb, 2048, 6144, 2048, 2048, 2048, 6144);

    attn_fwd<<<dim3(32, 16), dim3(256), 0, stream>>>(qkvb, vtb, qkvb);

    gemm_bb<0, 0, 64><<<dim3(16, 32), dim3(256), 0, stream>>>(
        qkvb + 4096, wpb, (void*)out, nullptr, 2048, 2048, 2048, 6144, 2048, 2048);
  } else {
    // fallback (32 MiB): fused fp32-convert GEMMs (round-4 structure)
    gemm_bt<1, 1, 1, 1, 128><<<dim3(48, 16), dim3(256), 0, stream>>>(
        x, w_attn, (void*)qkvb, vtb, 2048, 6144, 2048, 2048, 2048, 6144);

    attn_fwd<<<dim3(32, 16), dim3(256), 0, stream>>>(qkvb, vtb, qkvb);

    gemm_bt<0, 1, 0, 0, 64><<<dim3(16, 32), dim3(256), 0, stream>>>(
        (const void*)(qkvb + 4096), w_proj, (void*)out, nullptr, 2048, 2048, 2048, 6144, 2048, 2048);
  }
}